// Round 3
// baseline (3697.360 us; speedup 1.0000x reference)
//
#include <hip/hip_runtime.h>
#include <hip/hip_bf16.h>

// GatedGraphX: N=4096 nodes, H=64 hidden, IN=64, E=10 edge types, 10 iterations.
// R3 structure:
//   k_transpose: edge f32 [e][m][n] -> edgeT bf16 [e][n][m]  (once)
//   per iteration:
//     kA: act[e] = edgeT[e] @ h + ba  -- STREAMING register GEMM:
//         A (edgeT) has zero reuse -> fragments loaded global->VGPR directly,
//         B (hT, 512 KB, L2-resident) likewise. No LDS, no barriers in the
//         main loop; 2-deep register pipeline; waves block individually on
//         vmcnt so HBM stays saturated (Little's law: ~20 KB A in flight/CU
//         vs 9.2 KB needed). Writes act tiles bf16 (coalesced via LDS repack).
//     kB: S = sum_e act[e] @ W[e] as ONE K=640 register GEMM (replaces the
//         7.9M-atomics epilogue of R0-R2), + gates (uzur GEMM, sigmoid,
//         rh@uh GEMM, tanh, h update). S/atomics/S-reset eliminated.

typedef __bf16 bf16;
typedef bf16 bf16x8 __attribute__((ext_vector_type(8)));
typedef float f32x4 __attribute__((ext_vector_type(4)));

static_assert(sizeof(bf16) == 2, "bf16 size");

constexpr int kN = 4096;
constexpr int kH = 64;
constexpr int kE = 10;
constexpr int kIter = 10;

// workspace layout (bytes)
constexpr size_t OFF_EDGET = 0;                                    // [E][N][N] bf16
constexpr size_t SZ_EDGET  = (size_t)kE * kN * kN * 2;             // 335,544,320
constexpr size_t OFF_HF32  = OFF_EDGET + SZ_EDGET;                 // [N][H] f32
constexpr size_t OFF_HBF   = OFF_HF32 + (size_t)kN * kH * 4;       // [N][H] bf16
constexpr size_t OFF_HT    = OFF_HBF + (size_t)kN * kH * 2;        // [H][N] bf16
constexpr size_t OFF_ACT   = OFF_HT + (size_t)kN * kH * 2;         // [E][N][64] bf16
constexpr size_t OFF_SBIAS = OFF_ACT + (size_t)kE * kN * 64 * 2;   // [N][192] f32
constexpr size_t OFF_WT    = OFF_SBIAS + (size_t)kN * 192 * 4;     // [E][192][64] bf16
constexpr size_t OFF_UZT   = OFF_WT + (size_t)kE * 192 * 64 * 2;   // [128][64] bf16
constexpr size_t OFF_UHT   = OFF_UZT + (size_t)128 * 64 * 2;       // [64][64] bf16
constexpr size_t WS_NEEDED = OFF_UHT + (size_t)64 * 64 * 2;

__device__ __forceinline__ float sigmoidf_(float x) { return 1.0f / (1.0f + __expf(-x)); }
__device__ __forceinline__ float tanhf_(float x) { return 1.0f - 2.0f / (__expf(2.0f * x) + 1.0f); }

// ---------------- setup kernels ----------------

// edge [e][m][n] f32  ->  edgeT [e][n][m] bf16
__global__ __launch_bounds__(256) void k_transpose(const float* __restrict__ edge,
                                                   bf16* __restrict__ edgeT) {
  const int e = blockIdx.z;
  const int m0 = blockIdx.y * 64;
  const int n0 = blockIdx.x * 64;
  __shared__ bf16 t[64 * 66];
  const float* src = edge + (size_t)e * kN * kN;
  for (int i = threadIdx.x; i < 4096; i += 256) {
    int m = i >> 6, n = i & 63;
    t[n * 66 + m] = (bf16)src[(size_t)(m0 + m) * kN + n0 + n];
  }
  __syncthreads();
  bf16* dst = edgeT + (size_t)e * kN * kN;
  for (int i = threadIdx.x; i < 4096; i += 256) {
    int n = i >> 6, m = i & 63;
    dst[(size_t)(n0 + n) * kN + m0 + m] = t[n * 66 + m];
  }
}

// WT_all[e][c][hh] = W[e][hh][c];  uzurT[c][hh] = uz_ur[hh][c];  uhT[c][hh] = uh[hh][c]
__global__ __launch_bounds__(256) void k_weights(const float* __restrict__ wzwrwh,
                                                 const float* __restrict__ uz_ur,
                                                 const float* __restrict__ uh,
                                                 bf16* __restrict__ WT_all,
                                                 bf16* __restrict__ uzurT,
                                                 bf16* __restrict__ uhT) {
  int idx = blockIdx.x * 256 + threadIdx.x;
  if (idx < kE * 192 * 64) {
    int e = idx / (192 * 64);
    int rem = idx % (192 * 64);
    int c = rem / 64, hh = rem % 64;
    WT_all[idx] = (bf16)wzwrwh[((size_t)e * 64 + hh) * 192 + c];
  }
  if (idx < 128 * 64) {
    int c = idx / 64, hh = idx % 64;
    uzurT[idx] = (bf16)uz_ur[hh * 128 + c];
  }
  if (idx < 64 * 64) {
    int c = idx / 64, hh = idx % 64;
    uhT[idx] = (bf16)uh[hh * 64 + c];
  }
}

__global__ __launch_bounds__(256) void k_hinit(const float* __restrict__ hidden,
                                               float* __restrict__ hf32,
                                               bf16* __restrict__ hbf,
                                               bf16* __restrict__ hT) {
  int idx = blockIdx.x * 256 + threadIdx.x;  // < N*H
  float x = hidden[idx];
  hf32[idx] = x;
  hbf[idx] = (bf16)x;
  int n = idx >> 6, c = idx & 63;
  hT[(size_t)c * kN + n] = (bf16)x;
}

// SBias = E * (input @ input_wzrh)
__global__ __launch_bounds__(256) void k_sbias(const float* __restrict__ input,
                                               const float* __restrict__ input_wzrh,
                                               float* __restrict__ SBias) {
  int idx = blockIdx.x * 256 + threadIdx.x;  // < N*192
  int n = idx / 192, c = idx % 192;
  float a = 0.f;
#pragma unroll 8
  for (int k = 0; k < 64; k++) a += input[n * 64 + k] * input_wzrh[k * 192 + c];
  SBias[idx] = a * (float)kE;
}

// fallback if workspace too small: just copy hidden -> out (defined output)
__global__ __launch_bounds__(256) void k_copy(const float* __restrict__ src, float* __restrict__ dst) {
  int idx = blockIdx.x * 256 + threadIdx.x;
  dst[idx] = src[idx];
}

// ---------------- kA: act[e] = edgeT[e] @ h + ba (streaming, no LDS GEMM) ----
// grid (N/64, E); block 256 = 4 waves; wave w owns rows [w*16, w*16+16).
// Fragment mapping (verified lineage from R0-R2 working kernel):
//   A lane: row = n0 + w*16 + l15, k = k0 + ks*32 + q*8 .. +8
//   B lane: col = ct*16 + l15,     k = same        (B rows are hT rows = cols of h)
//   C lane: row = w*16 + q*4 + r,  col = ct*16 + l15
__global__ __launch_bounds__(256) void kA(const bf16* __restrict__ edgeT,
                                          const bf16* __restrict__ hT,
                                          const float* __restrict__ ba,
                                          bf16* __restrict__ actAll) {
  const int e = blockIdx.y;
  const int n0 = blockIdx.x * 64;
  const int tid = threadIdx.x;
  const int lane = tid & 63;
  const int w = tid >> 6;
  const int l15 = lane & 15;
  const int q = lane >> 4;

  __shared__ bf16 actlds[64 * 72];  // only for the coalesced output repack

  const bf16* aRow = edgeT + (size_t)e * kN * kN + (size_t)(n0 + w * 16 + l15) * kN + q * 8;
  const bf16* bRow0 = hT + (size_t)(0 * 16 + l15) * kN + q * 8;
  const bf16* bRow1 = hT + (size_t)(1 * 16 + l15) * kN + q * 8;
  const bf16* bRow2 = hT + (size_t)(2 * 16 + l15) * kN + q * 8;
  const bf16* bRow3 = hT + (size_t)(3 * 16 + l15) * kN + q * 8;

  f32x4 acc[4] = {};

  bf16x8 a0[2], a1[2];
  bf16x8 b0[2][4], b1[2][4];

#define LOADK(K0, A, B)                                    \
  {                                                        \
    _Pragma("unroll") for (int ks = 0; ks < 2; ks++) {     \
      int ko = (K0) + ks * 32;                             \
      A[ks] = *(const bf16x8*)(aRow + ko);                 \
      B[ks][0] = *(const bf16x8*)(bRow0 + ko);             \
      B[ks][1] = *(const bf16x8*)(bRow1 + ko);             \
      B[ks][2] = *(const bf16x8*)(bRow2 + ko);             \
      B[ks][3] = *(const bf16x8*)(bRow3 + ko);             \
    }                                                      \
  }
#define MFMAK(A, B)                                                                        \
  {                                                                                        \
    _Pragma("unroll") for (int ks = 0; ks < 2; ks++) {                                     \
      _Pragma("unroll") for (int ct = 0; ct < 4; ct++) {                                   \
        acc[ct] = __builtin_amdgcn_mfma_f32_16x16x32_bf16(A[ks], B[ks][ct], acc[ct], 0, 0, 0); \
      }                                                                                    \
    }                                                                                      \
  }

  // 2-deep register pipeline over K; no barriers anywhere in this loop.
  LOADK(0, a0, b0)
  for (int k0 = 0; k0 < kN; k0 += 128) {
    LOADK(k0 + 64, a1, b1)
    MFMAK(a0, b0)
    if (k0 + 128 < kN) LOADK(k0 + 128, a0, b0)
    MFMAK(a1, b1)
  }
#undef LOADK
#undef MFMAK

  // epilogue: acc + ba -> LDS repack -> coalesced bf16 store of act tile
#pragma unroll
  for (int ct = 0; ct < 4; ct++) {
    int col = ct * 16 + l15;
    float bav = ba[col];
#pragma unroll
    for (int r = 0; r < 4; r++) {
      actlds[(w * 16 + q * 4 + r) * 72 + col] = (bf16)(acc[ct][r] + bav);
    }
  }
  __syncthreads();
  bf16* dstp = actAll + ((size_t)e * kN + n0) * 64;
  for (int i = tid; i < 512; i += 256) {
    int row = i >> 3, col = (i & 7) * 8;
    *(int4*)(dstp + (size_t)row * 64 + col) = *(const int4*)(actlds + row * 72 + col);
  }
}

// ---------------- kB: fused sum_e act@W GEMM + gates + update ----------------
// grid N/64 blocks; block 256 = 4 waves; wave w owns rows [w*16, w*16+16)
__global__ __launch_bounds__(256) void kB(const bf16* __restrict__ actAll,
                                          const bf16* __restrict__ WT_all,
                                          const float* __restrict__ SBias,
                                          const bf16* __restrict__ hbf,
                                          const float* __restrict__ hf32,
                                          const bf16* __restrict__ uzurT,
                                          const bf16* __restrict__ uhT,
                                          float* __restrict__ hf32_out,
                                          bf16* __restrict__ hbf_out,
                                          bf16* __restrict__ hT_out,
                                          float* __restrict__ dst) {
  const int n0 = blockIdx.x * 64;
  const int tid = threadIdx.x;
  const int lane = tid & 63;
  const int w = tid >> 6;
  const int l15 = lane & 15;
  const int q = lane >> 4;

  __shared__ bf16 hA[64 * 72];    // h tile [n][hh]
  __shared__ bf16 uzT[128 * 72];  // uzurT [c][hh]
  __shared__ bf16 uhl[64 * 72];   // uhT [c][hh]
  __shared__ bf16 rhl[64 * 72];   // rh tile, reused for h_new transpose

  for (int i = tid; i < 64 * 8; i += 256) {
    int row = i >> 3, col = (i & 7) * 8;
    *(int4*)(hA + row * 72 + col) = *(const int4*)(hbf + (size_t)(n0 + row) * 64 + col);
  }
  for (int i = tid; i < 128 * 8; i += 256) {
    int row = i >> 3, col = (i & 7) * 8;
    *(int4*)(uzT + row * 72 + col) = *(const int4*)(uzurT + (size_t)row * 64 + col);
  }
  for (int i = tid; i < 64 * 8; i += 256) {
    int row = i >> 3, col = (i & 7) * 8;
    *(int4*)(uhl + row * 72 + col) = *(const int4*)(uhT + (size_t)row * 64 + col);
  }

  // GEMM_S: S_tile[64][192] = sum_e act[e]_tile @ W[e]  (K = E*64 = 640),
  // fragments straight from global (act: streamed once; WT_all: L2-resident).
  f32x4 acc2[12] = {};
  {
    const bf16* aBase = actAll + (size_t)(n0 + w * 16 + l15) * 64 + q * 8;
    const bf16* wBase = WT_all + (size_t)l15 * 64 + q * 8;
    for (int e = 0; e < kE; e++) {
      const bf16* ap = aBase + (size_t)e * kN * 64;
      const bf16* wp = wBase + (size_t)e * 192 * 64;
#pragma unroll
      for (int ks = 0; ks < 2; ks++) {
        bf16x8 af = *(const bf16x8*)(ap + ks * 32);
#pragma unroll
        for (int ct = 0; ct < 12; ct++) {
          bf16x8 bf = *(const bf16x8*)(wp + ct * 16 * 64 + ks * 32);
          acc2[ct] = __builtin_amdgcn_mfma_f32_16x16x32_bf16(af, bf, acc2[ct], 0, 0, 0);
        }
      }
    }
  }
  __syncthreads();  // staging (hA/uzT/uhl) visible

  // GEMM1: uzur[16 rows, 128] = h_tile @ uz_ur
  f32x4 u[8] = {};
#pragma unroll
  for (int ks = 0; ks < 2; ks++) {
    bf16x8 af = *(const bf16x8*)(hA + (w * 16 + l15) * 72 + ks * 32 + q * 8);
#pragma unroll
    for (int ct = 0; ct < 8; ct++) {
      bf16x8 bf = *(const bf16x8*)(uzT + (ct * 16 + l15) * 72 + ks * 32 + q * 8);
      u[ct] = __builtin_amdgcn_mfma_f32_16x16x32_bf16(af, bf, u[ct], 0, 0, 0);
    }
  }

  // gates z, r;  rh -> LDS
  float zv[4][4], hv[4][4];
#pragma unroll
  for (int ct = 0; ct < 4; ct++) {
    int col = ct * 16 + l15;
#pragma unroll
    for (int r = 0; r < 4; r++) {
      int row = n0 + w * 16 + q * 4 + r;
      float sz = SBias[(size_t)row * 192 + col] + acc2[ct][r];
      float sr = SBias[(size_t)row * 192 + 64 + col] + acc2[4 + ct][r];
      float z = sigmoidf_(sz + u[ct][r]);
      float rr = sigmoidf_(sr + u[4 + ct][r]);
      float h = hf32[(size_t)row * 64 + col];
      zv[ct][r] = z;
      hv[ct][r] = h;
      rhl[(w * 16 + q * 4 + r) * 72 + col] = (bf16)(rr * h);
    }
  }
  __syncthreads();

  // GEMM2: ht[16 rows, 64] = rh @ uh
  f32x4 t[4] = {};
#pragma unroll
  for (int ks = 0; ks < 2; ks++) {
    bf16x8 af = *(const bf16x8*)(rhl + (w * 16 + l15) * 72 + ks * 32 + q * 8);
#pragma unroll
    for (int ct = 0; ct < 4; ct++) {
      bf16x8 bf = *(const bf16x8*)(uhl + (ct * 16 + l15) * 72 + ks * 32 + q * 8);
      t[ct] = __builtin_amdgcn_mfma_f32_16x16x32_bf16(af, bf, t[ct], 0, 0, 0);
    }
  }

  // update
  float hn[4][4];
#pragma unroll
  for (int ct = 0; ct < 4; ct++) {
    int col = ct * 16 + l15;
#pragma unroll
    for (int r = 0; r < 4; r++) {
      int row = n0 + w * 16 + q * 4 + r;
      float wh = SBias[(size_t)row * 192 + 128 + col] + acc2[8 + ct][r];
      float htl = tanhf_(wh + t[ct][r]);
      float z = zv[ct][r];
      float v = (1.0f - z) * hv[ct][r] + z * htl;
      hn[ct][r] = v;
      dst[(size_t)row * 64 + col] = v;
      if (dst != hf32_out) hf32_out[(size_t)row * 64 + col] = v;
      hbf_out[(size_t)row * 64 + col] = (bf16)v;
    }
  }
  __syncthreads();  // all reads of rhl done

  // h_new -> LDS for transpose -> hT_out
#pragma unroll
  for (int ct = 0; ct < 4; ct++) {
#pragma unroll
    for (int r = 0; r < 4; r++) {
      int row = w * 16 + q * 4 + r, col = ct * 16 + l15;
      rhl[row * 72 + col] = (bf16)hn[ct][r];
    }
  }
  __syncthreads();
  for (int i = tid; i < 4096; i += 256) {
    int c = i >> 6, n = i & 63;
    hT_out[(size_t)c * kN + n0 + n] = rhl[n * 72 + c];
  }
}

extern "C" void kernel_launch(void* const* d_in, const int* in_sizes, int n_in,
                              void* d_out, int out_size, void* d_ws, size_t ws_size,
                              hipStream_t stream) {
  const float* input = (const float*)d_in[0];
  const float* hidden = (const float*)d_in[1];
  const float* edge = (const float*)d_in[2];
  const float* ba = (const float*)d_in[3];
  const float* wzwrwh = (const float*)d_in[4];
  const float* uz_ur = (const float*)d_in[5];
  const float* uh = (const float*)d_in[6];
  const float* input_wzrh = (const float*)d_in[7];
  float* out = (float*)d_out;

  if (ws_size < WS_NEEDED) {  // graceful (wrong but defined) fallback; signals ws too small
    k_copy<<<kN * kH / 256, 256, 0, stream>>>(hidden, out);
    return;
  }

  char* ws = (char*)d_ws;
  bf16* edgeT = (bf16*)(ws + OFF_EDGET);
  float* hf32 = (float*)(ws + OFF_HF32);
  bf16* hbf = (bf16*)(ws + OFF_HBF);
  bf16* hT = (bf16*)(ws + OFF_HT);
  bf16* actAll = (bf16*)(ws + OFF_ACT);
  float* SBias = (float*)(ws + OFF_SBIAS);
  bf16* WT_all = (bf16*)(ws + OFF_WT);
  bf16* uzurT = (bf16*)(ws + OFF_UZT);
  bf16* uhT = (bf16*)(ws + OFF_UHT);

  k_transpose<<<dim3(kN / 64, kN / 64, kE), 256, 0, stream>>>(edge, edgeT);
  k_weights<<<(kE * 192 * 64) / 256, 256, 0, stream>>>(wzwrwh, uz_ur, uh, WT_all, uzurT, uhT);
  k_hinit<<<(kN * kH) / 256, 256, 0, stream>>>(hidden, hf32, hbf, hT);
  k_sbias<<<(kN * 192) / 256, 256, 0, stream>>>(input, input_wzrh, SBias);

  for (int it = 0; it < kIter; it++) {
    kA<<<dim3(kN / 64, kE), 256, 0, stream>>>(edgeT, hT, ba, actAll);
    float* dst = (it == kIter - 1) ? out : hf32;
    kB<<<kN / 64, 256, 0, stream>>>(actAll, WT_all, SBias, hbf, hf32, uzurT, uhT,
                                    hf32, hbf, hT, dst);
  }
}

// Round 4
// 2130.165 us; speedup vs baseline: 1.7357x; 1.7357x over previous
//
#include <hip/hip_runtime.h>
#include <hip/hip_bf16.h>

// GatedGraphX: N=4096 nodes, H=64 hidden, IN=64, E=10 edge types, 10 iterations.
// R4 structure (base = R1, the best measured):
//   k_transpose: edge f32 [e][m][n] -> edgeT bf16 [e][n][m]  (once)
//   per iteration:
//     kA: act[e] = edgeT[e] @ h + ba (staged LDS GEMM, R1 swizzle), fused
//         epilogue act @ W[e] -> PLAIN STORES to exclusive Spart[e][n][192].
//         (R0-R3 used 7.9M contended cross-XCD f32 atomicAdds here -- the
//          hypothesized ~100us/launch cost none of the main-loop edits touched.)
//     kB: Slds = SBias + sum_e Spart[e] (coalesced pre-pass), then gates
//         (uzur GEMM, sigmoid, rh@uh GEMM, tanh, h update). No S reset.

typedef __bf16 bf16;
typedef bf16 bf16x8 __attribute__((ext_vector_type(8)));
typedef float f32x4 __attribute__((ext_vector_type(4)));

static_assert(sizeof(bf16) == 2, "bf16 size");

constexpr int kN = 4096;
constexpr int kH = 64;
constexpr int kE = 10;
constexpr int kIter = 10;

// workspace layout (bytes)
constexpr size_t OFF_EDGET = 0;                                      // [E][N][N] bf16
constexpr size_t SZ_EDGET  = (size_t)kE * kN * kN * 2;               // 335,544,320
constexpr size_t OFF_HF32  = OFF_EDGET + SZ_EDGET;                   // [N][H] f32
constexpr size_t OFF_HBF   = OFF_HF32 + (size_t)kN * kH * 4;         // [N][H] bf16
constexpr size_t OFF_HT    = OFF_HBF + (size_t)kN * kH * 2;          // [H][N] bf16
constexpr size_t OFF_SPART = OFF_HT + (size_t)kN * kH * 2;           // [E][N][192] f32
constexpr size_t OFF_SBIAS = OFF_SPART + (size_t)kE * kN * 192 * 4;  // [N][192] f32
constexpr size_t OFF_WT    = OFF_SBIAS + (size_t)kN * 192 * 4;       // [E][192][64] bf16
constexpr size_t OFF_UZT   = OFF_WT + (size_t)kE * 192 * 64 * 2;     // [128][64] bf16
constexpr size_t OFF_UHT   = OFF_UZT + (size_t)128 * 64 * 2;         // [64][64] bf16
constexpr size_t WS_NEEDED = OFF_UHT + (size_t)64 * 64 * 2;

__device__ __forceinline__ void async16(const void* g, void* l) {
  __builtin_amdgcn_global_load_lds(
      (const __attribute__((address_space(1))) unsigned int*)g,
      (__attribute__((address_space(3))) unsigned int*)l, 16, 0, 0);
}

__device__ __forceinline__ float sigmoidf_(float x) { return 1.0f / (1.0f + __expf(-x)); }
__device__ __forceinline__ float tanhf_(float x) { return 1.0f - 2.0f / (__expf(2.0f * x) + 1.0f); }

// ---------------- setup kernels ----------------

// edge [e][m][n] f32  ->  edgeT [e][n][m] bf16
__global__ __launch_bounds__(256) void k_transpose(const float* __restrict__ edge,
                                                   bf16* __restrict__ edgeT) {
  const int e = blockIdx.z;
  const int m0 = blockIdx.y * 64;
  const int n0 = blockIdx.x * 64;
  __shared__ bf16 t[64 * 66];
  const float* src = edge + (size_t)e * kN * kN;
  for (int i = threadIdx.x; i < 4096; i += 256) {
    int m = i >> 6, n = i & 63;
    t[n * 66 + m] = (bf16)src[(size_t)(m0 + m) * kN + n0 + n];
  }
  __syncthreads();
  bf16* dst = edgeT + (size_t)e * kN * kN;
  for (int i = threadIdx.x; i < 4096; i += 256) {
    int n = i >> 6, m = i & 63;
    dst[(size_t)(n0 + n) * kN + m0 + m] = t[n * 66 + m];
  }
}

// WT_all[e][c][hh] = W[e][hh][c];  uzurT[c][hh] = uz_ur[hh][c];  uhT[c][hh] = uh[hh][c]
__global__ __launch_bounds__(256) void k_weights(const float* __restrict__ wzwrwh,
                                                 const float* __restrict__ uz_ur,
                                                 const float* __restrict__ uh,
                                                 bf16* __restrict__ WT_all,
                                                 bf16* __restrict__ uzurT,
                                                 bf16* __restrict__ uhT) {
  int idx = blockIdx.x * 256 + threadIdx.x;
  if (idx < kE * 192 * 64) {
    int e = idx / (192 * 64);
    int rem = idx % (192 * 64);
    int c = rem / 64, hh = rem % 64;
    WT_all[idx] = (bf16)wzwrwh[((size_t)e * 64 + hh) * 192 + c];
  }
  if (idx < 128 * 64) {
    int c = idx / 64, hh = idx % 64;
    uzurT[idx] = (bf16)uz_ur[hh * 128 + c];
  }
  if (idx < 64 * 64) {
    int c = idx / 64, hh = idx % 64;
    uhT[idx] = (bf16)uh[hh * 64 + c];
  }
}

__global__ __launch_bounds__(256) void k_hinit(const float* __restrict__ hidden,
                                               float* __restrict__ hf32,
                                               bf16* __restrict__ hbf,
                                               bf16* __restrict__ hT) {
  int idx = blockIdx.x * 256 + threadIdx.x;  // < N*H
  float x = hidden[idx];
  hf32[idx] = x;
  hbf[idx] = (bf16)x;
  int n = idx >> 6, c = idx & 63;
  hT[(size_t)c * kN + n] = (bf16)x;
}

// SBias = E * (input @ input_wzrh)
__global__ __launch_bounds__(256) void k_sbias(const float* __restrict__ input,
                                               const float* __restrict__ input_wzrh,
                                               float* __restrict__ SBias) {
  int idx = blockIdx.x * 256 + threadIdx.x;  // < N*192
  int n = idx / 192, c = idx % 192;
  float a = 0.f;
#pragma unroll 8
  for (int k = 0; k < 64; k++) a += input[n * 64 + k] * input_wzrh[k * 192 + c];
  SBias[idx] = a * (float)kE;
}

// fallback if workspace too small: just copy hidden -> out (defined output)
__global__ __launch_bounds__(256) void k_copy(const float* __restrict__ src, float* __restrict__ dst) {
  int idx = blockIdx.x * 256 + threadIdx.x;
  dst[idx] = src[idx];
}

// ---------------- main GEMM kernel (per edge type) ----------------
// grid (N/64, E); block 256 = 4 waves; wave w owns rows [w*16, w*16+16).
// Main loop = R1's proven structure: single-buffer global_load_lds staging
// with pre-swizzled global source + XOR'd LDS reads (G21 both-sides).
// Epilogue: GEMM2 (act @ W[e]) with W-frags from L2-resident global (as R2),
// results stored PLAIN (exclusive ownership) to Spart[e] -- no atomics.
__global__ __launch_bounds__(256) void kA(const bf16* __restrict__ edgeT,
                                          const bf16* __restrict__ hT,
                                          const bf16* __restrict__ WT_all,
                                          const float* __restrict__ ba,
                                          float* __restrict__ Spart) {
  const int e = blockIdx.y;
  const int n0 = blockIdx.x * 64;
  const int tid = threadIdx.x;
  const int lane = tid & 63;
  const int w = tid >> 6;
  const int l15 = lane & 15;
  const int q = lane >> 4;

  __shared__ bf16 Alds[64 * 64];    // [n][k] rows 128B, XOR-swizzled content
  __shared__ bf16 Blds[64 * 64];    // [h][k], XOR-swizzled content
  __shared__ bf16 actlds[64 * 72];  // padded stride 72 elems (144B)

  f32x4 acc[4] = {};
  const bf16* Abase = edgeT + (size_t)e * kN * kN + (size_t)n0 * kN;

  for (int k0 = 0; k0 < kN; k0 += 64) {
    __syncthreads();
#pragma unroll
    for (int i = 0; i < 2; i++) {
      int c = i * 256 + tid;
      int row = c >> 3;
      int col = ((c & 7) ^ (row & 7)) * 8;  // pre-swizzled global source
      async16(Abase + (size_t)row * kN + k0 + col, Alds + c * 8);
    }
#pragma unroll
    for (int i = 0; i < 2; i++) {
      int c = i * 256 + tid;
      int row = c >> 3;
      int col = ((c & 7) ^ (row & 7)) * 8;  // pre-swizzled global source
      async16(hT + (size_t)row * kN + k0 + col, Blds + c * 8);
    }
    __syncthreads();  // vmcnt(0) drain: tile ready
#pragma unroll
    for (int ks = 0; ks < 2; ks++) {
      const int ar = w * 16 + l15;
      bf16x8 af = *(const bf16x8*)(Alds + ar * 64 + ((ks * 32 + q * 8) ^ ((ar & 7) << 3)));
#pragma unroll
      for (int ct = 0; ct < 4; ct++) {
        const int br = ct * 16 + l15;
        bf16x8 bf = *(const bf16x8*)(Blds + br * 64 + ((ks * 32 + q * 8) ^ ((br & 7) << 3)));
        acc[ct] = __builtin_amdgcn_mfma_f32_16x16x32_bf16(af, bf, acc[ct], 0, 0, 0);
      }
    }
  }

  // epilogue: act = acc + ba[col] -> LDS (A-operand layout for GEMM2)
  __syncthreads();
#pragma unroll
  for (int ct = 0; ct < 4; ct++) {
    int col = ct * 16 + l15;
    float bav = ba[col];
#pragma unroll
    for (int r = 0; r < 4; r++) {
      int row = w * 16 + q * 4 + r;
      actlds[row * 72 + col] = (bf16)(acc[ct][r] + bav);
    }
  }
  __syncthreads();

  // GEMM2: S_part[16 rows, 192] = act_tile @ W[e]; W-frags from global (L2:
  // 24 KB/e shared by 64 blocks).
  const bf16* Wg = WT_all + (size_t)e * 192 * 64;
  f32x4 acc2[12] = {};
#pragma unroll
  for (int ks = 0; ks < 2; ks++) {
    bf16x8 af = *(const bf16x8*)(actlds + (w * 16 + l15) * 72 + ks * 32 + q * 8);
#pragma unroll
    for (int ct = 0; ct < 12; ct++) {
      bf16x8 bf = *(const bf16x8*)(Wg + (ct * 16 + l15) * 64 + ks * 32 + q * 8);
      acc2[ct] = __builtin_amdgcn_mfma_f32_16x16x32_bf16(af, bf, acc2[ct], 0, 0, 0);
    }
  }

  // plain stores to exclusive Spart[e] tile (no atomics, no contention)
  float* Sp = Spart + (size_t)e * kN * 192;
#pragma unroll
  for (int ct = 0; ct < 12; ct++) {
    int col = ct * 16 + l15;
#pragma unroll
    for (int r = 0; r < 4; r++) {
      int row = n0 + w * 16 + q * 4 + r;
      Sp[(size_t)row * 192 + col] = acc2[ct][r];
    }
  }
}

// ---------------- gate / update kernel ----------------
// grid N/64 blocks; block 256 = 4 waves; wave w owns rows [w*16, w*16+16)
__global__ __launch_bounds__(256) void kB(const float* __restrict__ Spart,
                                          const float* __restrict__ SBias,
                                          const bf16* __restrict__ hbf,
                                          const float* __restrict__ hf32,
                                          const bf16* __restrict__ uzurT,
                                          const bf16* __restrict__ uhT,
                                          float* __restrict__ hf32_out,
                                          bf16* __restrict__ hbf_out,
                                          bf16* __restrict__ hT_out,
                                          float* __restrict__ dst) {
  const int n0 = blockIdx.x * 64;
  const int tid = threadIdx.x;
  const int lane = tid & 63;
  const int w = tid >> 6;
  const int l15 = lane & 15;
  const int q = lane >> 4;

  __shared__ float Slds[64 * 193];  // summed S tile, stride 193 (breaks 4-way)
  __shared__ bf16 hA[64 * 72];      // h tile [n][hh]
  __shared__ bf16 uzT[128 * 72];    // uzurT [c][hh]
  __shared__ bf16 uhl[64 * 72];     // uhT [c][hh]
  __shared__ bf16 rhl[64 * 72];     // rh tile, reused for h_new transpose

  for (int i = tid; i < 64 * 8; i += 256) {
    int row = i >> 3, col = (i & 7) * 8;
    *(int4*)(hA + row * 72 + col) = *(const int4*)(hbf + (size_t)(n0 + row) * 64 + col);
  }
  for (int i = tid; i < 128 * 8; i += 256) {
    int row = i >> 3, col = (i & 7) * 8;
    *(int4*)(uzT + row * 72 + col) = *(const int4*)(uzurT + (size_t)row * 64 + col);
  }
  for (int i = tid; i < 64 * 8; i += 256) {
    int row = i >> 3, col = (i & 7) * 8;
    *(int4*)(uhl + row * 72 + col) = *(const int4*)(uhT + (size_t)row * 64 + col);
  }

  // pre-pass: Slds = SBias + sum_e Spart[e]  (fully coalesced reads)
  for (int i = tid; i < 64 * 192; i += 256) {
    int row = i / 192, col = i % 192;
    size_t g = (size_t)(n0 + row) * 192 + col;
    float s = SBias[g];
#pragma unroll
    for (int e = 0; e < kE; e++) s += Spart[(size_t)e * kN * 192 + g];
    Slds[row * 193 + col] = s;
  }
  __syncthreads();

  // GEMM1: uzur[16 rows, 128] = h_tile @ uz_ur
  f32x4 u[8] = {};
#pragma unroll
  for (int ks = 0; ks < 2; ks++) {
    bf16x8 af = *(const bf16x8*)(hA + (w * 16 + l15) * 72 + ks * 32 + q * 8);
#pragma unroll
    for (int ct = 0; ct < 8; ct++) {
      bf16x8 bf = *(const bf16x8*)(uzT + (ct * 16 + l15) * 72 + ks * 32 + q * 8);
      u[ct] = __builtin_amdgcn_mfma_f32_16x16x32_bf16(af, bf, u[ct], 0, 0, 0);
    }
  }

  // gates z, r;  rh -> LDS
  float zv[4][4], hv[4][4];
#pragma unroll
  for (int ct = 0; ct < 4; ct++) {
    int col = ct * 16 + l15;
#pragma unroll
    for (int r = 0; r < 4; r++) {
      int lrow = w * 16 + q * 4 + r;
      int row = n0 + lrow;
      float sz = Slds[lrow * 193 + col];
      float sr = Slds[lrow * 193 + 64 + col];
      float z = sigmoidf_(sz + u[ct][r]);
      float rr = sigmoidf_(sr + u[4 + ct][r]);
      float h = hf32[(size_t)row * 64 + col];
      zv[ct][r] = z;
      hv[ct][r] = h;
      rhl[lrow * 72 + col] = (bf16)(rr * h);
    }
  }
  __syncthreads();

  // GEMM2: ht[16 rows, 64] = rh @ uh
  f32x4 t[4] = {};
#pragma unroll
  for (int ks = 0; ks < 2; ks++) {
    bf16x8 af = *(const bf16x8*)(rhl + (w * 16 + l15) * 72 + ks * 32 + q * 8);
#pragma unroll
    for (int ct = 0; ct < 4; ct++) {
      bf16x8 bf = *(const bf16x8*)(uhl + (ct * 16 + l15) * 72 + ks * 32 + q * 8);
      t[ct] = __builtin_amdgcn_mfma_f32_16x16x32_bf16(af, bf, t[ct], 0, 0, 0);
    }
  }

  // update
  float hn[4][4];
#pragma unroll
  for (int ct = 0; ct < 4; ct++) {
    int col = ct * 16 + l15;
#pragma unroll
    for (int r = 0; r < 4; r++) {
      int lrow = w * 16 + q * 4 + r;
      int row = n0 + lrow;
      float wh = Slds[lrow * 193 + 128 + col];
      float htl = tanhf_(wh + t[ct][r]);
      float z = zv[ct][r];
      float v = (1.0f - z) * hv[ct][r] + z * htl;
      hn[ct][r] = v;
      dst[(size_t)row * 64 + col] = v;
      if (dst != hf32_out) hf32_out[(size_t)row * 64 + col] = v;
      hbf_out[(size_t)row * 64 + col] = (bf16)v;
    }
  }
  __syncthreads();  // all reads of rhl done

  // h_new -> LDS for transpose -> hT_out
#pragma unroll
  for (int ct = 0; ct < 4; ct++) {
#pragma unroll
    for (int r = 0; r < 4; r++) {
      int row = w * 16 + q * 4 + r, col = ct * 16 + l15;
      rhl[row * 72 + col] = (bf16)hn[ct][r];
    }
  }
  __syncthreads();
  for (int i = tid; i < 4096; i += 256) {
    int c = i >> 6, n = i & 63;
    hT_out[(size_t)c * kN + n0 + n] = rhl[n * 72 + c];
  }
}

extern "C" void kernel_launch(void* const* d_in, const int* in_sizes, int n_in,
                              void* d_out, int out_size, void* d_ws, size_t ws_size,
                              hipStream_t stream) {
  const float* input = (const float*)d_in[0];
  const float* hidden = (const float*)d_in[1];
  const float* edge = (const float*)d_in[2];
  const float* ba = (const float*)d_in[3];
  const float* wzwrwh = (const float*)d_in[4];
  const float* uz_ur = (const float*)d_in[5];
  const float* uh = (const float*)d_in[6];
  const float* input_wzrh = (const float*)d_in[7];
  float* out = (float*)d_out;

  if (ws_size < WS_NEEDED) {  // graceful (wrong but defined) fallback; signals ws too small
    k_copy<<<kN * kH / 256, 256, 0, stream>>>(hidden, out);
    return;
  }

  char* ws = (char*)d_ws;
  bf16* edgeT = (bf16*)(ws + OFF_EDGET);
  float* hf32 = (float*)(ws + OFF_HF32);
  bf16* hbf = (bf16*)(ws + OFF_HBF);
  bf16* hT = (bf16*)(ws + OFF_HT);
  float* Spart = (float*)(ws + OFF_SPART);
  float* SBias = (float*)(ws + OFF_SBIAS);
  bf16* WT_all = (bf16*)(ws + OFF_WT);
  bf16* uzurT = (bf16*)(ws + OFF_UZT);
  bf16* uhT = (bf16*)(ws + OFF_UHT);

  k_transpose<<<dim3(kN / 64, kN / 64, kE), 256, 0, stream>>>(edge, edgeT);
  k_weights<<<(kE * 192 * 64) / 256, 256, 0, stream>>>(wzwrwh, uz_ur, uh, WT_all, uzurT, uhT);
  k_hinit<<<(kN * kH) / 256, 256, 0, stream>>>(hidden, hf32, hbf, hT);
  k_sbias<<<(kN * 192) / 256, 256, 0, stream>>>(input, input_wzrh, SBias);

  for (int it = 0; it < kIter; it++) {
    kA<<<dim3(kN / 64, kE), 256, 0, stream>>>(edgeT, hT, WT_all, ba, Spart);
    float* dst = (it == kIter - 1) ? out : hf32;
    kB<<<kN / 64, 256, 0, stream>>>(Spart, SBias, hbf, hf32, uzurT, uhT,
                                    hf32, hbf, hT, dst);
  }
}